// Round 5
// baseline (543.298 us; speedup 1.0000x reference)
//
#include <hip/hip_runtime.h>

// Per-pixel attention over 32 "boxes" (all fp32):
//   q,k,v: [32 box][4 batch][64 ch][6400 pix]
//   scores[i,j] = <q[i,:,p], k[j,:,p]> / 8 ; w = softmax_j ; out[i,c,p] = sum_j w[i,j] v[j,c,p]
//
// R5 vs R4: R4 was latency/barrier-bound (VALU 27%, HBM 25%, occupancy 18%, nothing
// saturated; 64 barriers, 2 blocks/CU, 28% dispatch tail). Changes, all one mechanism
// (more independent streams, fewer barriers):
//   1. LDS double-buffer -> 1 barrier/chunk (32 total). Write targets the buffer whose
//      readers retired at the *previous* barrier (race-free by induction).
//   2. NT=256, PIX=16, __launch_bounds__(256,4): 4 blocks/CU (16 waves/CU @128 VGPR),
//      grid 1600 -> tail 12% (was 28%). LDS reads become 16-addr x 4-lane broadcast
//      (conflict-free); staging writes 2-way/bank (free, m136).
//   3. Chunked XCD swizzle (1600%8==0, bijective): tile pairs sharing a 128B line land
//      on the same XCD's L2.
// Thread t owns (pixel = t&15, queries i0 = (t>>4)*2); 32-wide score row in registers,
// softmax in-lane (1/8 scale folded into the exp argument).

#define NBOX    32
#define NBATCH  4
#define CH      64
#define HW      6400
#define PIX     16
#define CC      4            // channels per LDS chunk
#define NCHUNK  (CH / CC)    // 16
#define IB      2            // queries per thread
#define NT      256
#define LPJ     36           // LDS row stride in floats (32 j + 4 pad)
#define NTILES  (HW / PIX)   // 400
#define NUNITS  (NBATCH * NTILES)  // 1600

__device__ __forceinline__ void stage_load(const float* __restrict__ src, int b, int c0,
                                           int p0, int t, float4 r[2]) {
#pragma unroll
    for (int u = 0; u < 2; ++u) {
        int f  = u * NT + t;          // 0..511 ; f = c*128 + j*4 + pg (bijective)
        int pg = f & 3;               // pixel group of 4
        int j  = (f >> 2) & 31;       // box
        int c  = f >> 7;              // 0..3 channel within chunk
        const float* g = src + ((size_t)((j * NBATCH + b) * CH + (c0 + c)) * HW + p0 + pg * 4);
        r[u] = *reinterpret_cast<const float4*>(g);
    }
}

__device__ __forceinline__ void stage_write(float* lds, int t, const float4 r[2]) {
#pragma unroll
    for (int u = 0; u < 2; ++u) {
        int f  = u * NT + t;
        int pg = f & 3;
        int j  = (f >> 2) & 31;
        int c  = f >> 7;
        float* d = &lds[(c * PIX + pg * 4) * LPJ + j];
        d[0 * LPJ] = r[u].x;
        d[1 * LPJ] = r[u].y;
        d[2 * LPJ] = r[u].z;
        d[3 * LPJ] = r[u].w;
    }
}

__global__ __launch_bounds__(NT, 4)
void box_attn_kernel(const float* __restrict__ q,
                     const float* __restrict__ k,
                     const float* __restrict__ v,
                     float* __restrict__ out) {
    __shared__ float lds[2][CC * PIX * LPJ];   // 2 x 9.2 KiB

    const int t   = threadIdx.x;
    const int bid = blockIdx.x;
    // chunked XCD swizzle: each of the 8 XCDs gets a contiguous run of 200 units
    const int unit = (bid & 7) * (NUNITS / 8) + (bid >> 3);
    const int b    = unit / NTILES;
    const int p0   = (unit % NTILES) * PIX;

    const int pp = t & (PIX - 1);
    const int i0 = (t >> 4) * IB;   // first of this thread's 2 queries

    float s[IB][NBOX];
#pragma unroll
    for (int a = 0; a < IB; ++a)
#pragma unroll
        for (int j = 0; j < NBOX; ++j) s[a][j] = 0.f;

    float4 rb[2];

    // ---------------- Phase 1: scores = Q.K (unscaled; 1/8 folded into softmax) -------
    stage_load(k, b, 0, p0, t, rb);
    stage_write(&lds[0][0], t, rb);
    __syncthreads();
#pragma unroll
    for (int ch = 0; ch < NCHUNK; ++ch) {
        const int c0 = ch * CC;
        if (ch + 1 < NCHUNK) stage_load(k, b, c0 + CC, p0, t, rb);   // issue early

        float qf[IB][CC];
#pragma unroll
        for (int a = 0; a < IB; ++a)
#pragma unroll
            for (int c = 0; c < CC; ++c)
                qf[a][c] = q[(size_t)(((i0 + a) * NBATCH + b) * CH + (c0 + c)) * HW + p0 + pp];

        const float* buf = &lds[ch & 1][0];
#pragma unroll
        for (int c = 0; c < CC; ++c) {
#pragma unroll
            for (int jg = 0; jg < 8; ++jg) {
                float4 kv = *reinterpret_cast<const float4*>(&buf[(c * PIX + pp) * LPJ + jg * 4]);
#pragma unroll
                for (int a = 0; a < IB; ++a) {
                    s[a][jg * 4 + 0] = fmaf(qf[a][c], kv.x, s[a][jg * 4 + 0]);
                    s[a][jg * 4 + 1] = fmaf(qf[a][c], kv.y, s[a][jg * 4 + 1]);
                    s[a][jg * 4 + 2] = fmaf(qf[a][c], kv.z, s[a][jg * 4 + 2]);
                    s[a][jg * 4 + 3] = fmaf(qf[a][c], kv.w, s[a][jg * 4 + 3]);
                }
            }
        }
        if (ch + 1 < NCHUNK) stage_write(&lds[(ch + 1) & 1][0], t, rb);  // other buffer: no race
        __syncthreads();
    }

    // ---------------- softmax over j (in-register; scale folded) ----------------
    stage_load(v, b, 0, p0, t, rb);   // overlap V chunk-0 fetch with softmax
#pragma unroll
    for (int a = 0; a < IB; ++a) {
        float m = s[a][0];
#pragma unroll
        for (int j = 1; j < NBOX; ++j) m = fmaxf(m, s[a][j]);
        float sum = 0.f;
#pragma unroll
        for (int j = 0; j < NBOX; ++j) {
            float e = __expf((s[a][j] - m) * 0.125f);
            s[a][j] = e; sum += e;
        }
        float inv = 1.f / sum;
#pragma unroll
        for (int j = 0; j < NBOX; ++j) s[a][j] *= inv;
    }

    // ---------------- Phase 2: out = W V ----------------
    stage_write(&lds[0][0], t, rb);   // all waves are past the final phase-1 barrier
    __syncthreads();
#pragma unroll
    for (int ch = 0; ch < NCHUNK; ++ch) {
        const int c0 = ch * CC;
        if (ch + 1 < NCHUNK) stage_load(v, b, c0 + CC, p0, t, rb);

        float acc[IB][CC];
#pragma unroll
        for (int a = 0; a < IB; ++a)
#pragma unroll
            for (int c = 0; c < CC; ++c) acc[a][c] = 0.f;

        const float* buf = &lds[ch & 1][0];
#pragma unroll
        for (int c = 0; c < CC; ++c) {
#pragma unroll
            for (int jg = 0; jg < 8; ++jg) {
                float4 vv = *reinterpret_cast<const float4*>(&buf[(c * PIX + pp) * LPJ + jg * 4]);
#pragma unroll
                for (int a = 0; a < IB; ++a) {
                    acc[a][c] = fmaf(s[a][jg * 4 + 0], vv.x, acc[a][c]);
                    acc[a][c] = fmaf(s[a][jg * 4 + 1], vv.y, acc[a][c]);
                    acc[a][c] = fmaf(s[a][jg * 4 + 2], vv.z, acc[a][c]);
                    acc[a][c] = fmaf(s[a][jg * 4 + 3], vv.w, acc[a][c]);
                }
            }
        }
#pragma unroll
        for (int a = 0; a < IB; ++a)
#pragma unroll
            for (int c = 0; c < CC; ++c)
                out[(size_t)(((i0 + a) * NBATCH + b) * CH + (c0 + c)) * HW + p0 + pp] = acc[a][c];

        if (ch + 1 < NCHUNK) stage_write(&lds[(ch + 1) & 1][0], t, rb);
        __syncthreads();
    }
}

extern "C" void kernel_launch(void* const* d_in, const int* in_sizes, int n_in,
                              void* d_out, int out_size, void* d_ws, size_t ws_size,
                              hipStream_t stream) {
    const float* q = (const float*)d_in[0];
    const float* k = (const float*)d_in[1];
    const float* v = (const float*)d_in[2];
    float* o = (float*)d_out;
    dim3 grid(NUNITS);   // 1600 blocks of 256
    box_attn_kernel<<<grid, NT, 0, stream>>>(q, k, v, o);
}

// Round 6
// 291.007 us; speedup vs baseline: 1.8670x; 1.8670x over previous
//
#include <hip/hip_runtime.h>

// Per-pixel attention over 32 "boxes" (all fp32):
//   q,k,v: [32 box][4 batch][64 ch][6400 pix]
//   scores[i,j] = <q[i,:,p], k[j,:,p]> / 8 ; w = softmax_j ; out[i,c,p] = sum_j w[i,j] v[j,c,p]
//
// R6 vs R5: ONLY the launch_bounds knob. Empirical law on this compiler (3 data points):
//   VGPR cap = 256 / arg2, independent of block size:
//     (512,4)->64  (512,2)->128  (256,4)->64   [R3/R4/R5 rocprof VGPR_Count]
// R5's (256,4) re-imposed the 64-reg cap on ~110 live floats -> scratch spill thrash
// (WRITE 715 MB vs 210 MB output, dur 543us). Now (256,2) -> cap 128, proven spill-free
// in R4. Residency from ACTUAL usage: 128 VGPR -> 4 waves/SIMD -> 4 blocks/CU
// (LDS 4x18.4KiB=74KiB<160). Keeps R5's wins: double-buffered LDS (1 barrier/chunk,
// bank conflicts 9.8M->3.3M), PIX=16, chunked XCD swizzle, 1600-block grid (12% tail).
//
// Thread t owns (pixel = t&15, queries i0 = (t>>4)*2); 32-wide score row in registers,
// softmax in-lane (1/8 scale folded into the exp argument).

#define NBOX    32
#define NBATCH  4
#define CH      64
#define HW      6400
#define PIX     16
#define CC      4            // channels per LDS chunk
#define NCHUNK  (CH / CC)    // 16
#define IB      2            // queries per thread
#define NT      256
#define LPJ     36           // LDS row stride in floats (32 j + 4 pad)
#define NTILES  (HW / PIX)   // 400
#define NUNITS  (NBATCH * NTILES)  // 1600

__device__ __forceinline__ void stage_load(const float* __restrict__ src, int b, int c0,
                                           int p0, int t, float4 r[2]) {
#pragma unroll
    for (int u = 0; u < 2; ++u) {
        int f  = u * NT + t;          // 0..511 ; f = c*128 + j*4 + pg (bijective)
        int pg = f & 3;               // pixel group of 4
        int j  = (f >> 2) & 31;       // box
        int c  = f >> 7;              // 0..3 channel within chunk
        const float* g = src + ((size_t)((j * NBATCH + b) * CH + (c0 + c)) * HW + p0 + pg * 4);
        r[u] = *reinterpret_cast<const float4*>(g);
    }
}

__device__ __forceinline__ void stage_write(float* lds, int t, const float4 r[2]) {
#pragma unroll
    for (int u = 0; u < 2; ++u) {
        int f  = u * NT + t;
        int pg = f & 3;
        int j  = (f >> 2) & 31;
        int c  = f >> 7;
        float* d = &lds[(c * PIX + pg * 4) * LPJ + j];
        d[0 * LPJ] = r[u].x;
        d[1 * LPJ] = r[u].y;
        d[2 * LPJ] = r[u].z;
        d[3 * LPJ] = r[u].w;
    }
}

__global__ __launch_bounds__(NT, 2)
void box_attn_kernel(const float* __restrict__ q,
                     const float* __restrict__ k,
                     const float* __restrict__ v,
                     float* __restrict__ out) {
    __shared__ float lds[2][CC * PIX * LPJ];   // 2 x 9.2 KiB

    const int t   = threadIdx.x;
    const int bid = blockIdx.x;
    // chunked XCD swizzle: each of the 8 XCDs gets a contiguous run of 200 units
    const int unit = (bid & 7) * (NUNITS / 8) + (bid >> 3);
    const int b    = unit / NTILES;
    const int p0   = (unit % NTILES) * PIX;

    const int pp = t & (PIX - 1);
    const int i0 = (t >> 4) * IB;   // first of this thread's 2 queries

    float s[IB][NBOX];
#pragma unroll
    for (int a = 0; a < IB; ++a)
#pragma unroll
        for (int j = 0; j < NBOX; ++j) s[a][j] = 0.f;

    float4 rb[2];

    // ---------------- Phase 1: scores = Q.K (unscaled; 1/8 folded into softmax) -------
    stage_load(k, b, 0, p0, t, rb);
    stage_write(&lds[0][0], t, rb);
    __syncthreads();
#pragma unroll
    for (int ch = 0; ch < NCHUNK; ++ch) {
        const int c0 = ch * CC;
        if (ch + 1 < NCHUNK) stage_load(k, b, c0 + CC, p0, t, rb);   // issue early

        float qf[IB][CC];
#pragma unroll
        for (int a = 0; a < IB; ++a)
#pragma unroll
            for (int c = 0; c < CC; ++c)
                qf[a][c] = q[(size_t)(((i0 + a) * NBATCH + b) * CH + (c0 + c)) * HW + p0 + pp];

        const float* buf = &lds[ch & 1][0];
#pragma unroll
        for (int c = 0; c < CC; ++c) {
#pragma unroll
            for (int jg = 0; jg < 8; ++jg) {
                float4 kv = *reinterpret_cast<const float4*>(&buf[(c * PIX + pp) * LPJ + jg * 4]);
#pragma unroll
                for (int a = 0; a < IB; ++a) {
                    s[a][jg * 4 + 0] = fmaf(qf[a][c], kv.x, s[a][jg * 4 + 0]);
                    s[a][jg * 4 + 1] = fmaf(qf[a][c], kv.y, s[a][jg * 4 + 1]);
                    s[a][jg * 4 + 2] = fmaf(qf[a][c], kv.z, s[a][jg * 4 + 2]);
                    s[a][jg * 4 + 3] = fmaf(qf[a][c], kv.w, s[a][jg * 4 + 3]);
                }
            }
        }
        if (ch + 1 < NCHUNK) stage_write(&lds[(ch + 1) & 1][0], t, rb);  // other buffer: no race
        __syncthreads();
    }

    // ---------------- softmax over j (in-register; scale folded) ----------------
    stage_load(v, b, 0, p0, t, rb);   // overlap V chunk-0 fetch with softmax
#pragma unroll
    for (int a = 0; a < IB; ++a) {
        float m = s[a][0];
#pragma unroll
        for (int j = 1; j < NBOX; ++j) m = fmaxf(m, s[a][j]);
        float sum = 0.f;
#pragma unroll
        for (int j = 0; j < NBOX; ++j) {
            float e = __expf((s[a][j] - m) * 0.125f);
            s[a][j] = e; sum += e;
        }
        float inv = 1.f / sum;
#pragma unroll
        for (int j = 0; j < NBOX; ++j) s[a][j] *= inv;
    }

    // ---------------- Phase 2: out = W V ----------------
    stage_write(&lds[0][0], t, rb);   // all waves are past the final phase-1 barrier
    __syncthreads();
#pragma unroll
    for (int ch = 0; ch < NCHUNK; ++ch) {
        const int c0 = ch * CC;
        if (ch + 1 < NCHUNK) stage_load(v, b, c0 + CC, p0, t, rb);

        float acc[IB][CC];
#pragma unroll
        for (int a = 0; a < IB; ++a)
#pragma unroll
            for (int c = 0; c < CC; ++c) acc[a][c] = 0.f;

        const float* buf = &lds[ch & 1][0];
#pragma unroll
        for (int c = 0; c < CC; ++c) {
#pragma unroll
            for (int jg = 0; jg < 8; ++jg) {
                float4 vv = *reinterpret_cast<const float4*>(&buf[(c * PIX + pp) * LPJ + jg * 4]);
#pragma unroll
                for (int a = 0; a < IB; ++a) {
                    acc[a][c] = fmaf(s[a][jg * 4 + 0], vv.x, acc[a][c]);
                    acc[a][c] = fmaf(s[a][jg * 4 + 1], vv.y, acc[a][c]);
                    acc[a][c] = fmaf(s[a][jg * 4 + 2], vv.z, acc[a][c]);
                    acc[a][c] = fmaf(s[a][jg * 4 + 3], vv.w, acc[a][c]);
                }
            }
        }
#pragma unroll
        for (int a = 0; a < IB; ++a)
#pragma unroll
            for (int c = 0; c < CC; ++c)
                out[(size_t)(((i0 + a) * NBATCH + b) * CH + (c0 + c)) * HW + p0 + pp] = acc[a][c];

        if (ch + 1 < NCHUNK) stage_write(&lds[(ch + 1) & 1][0], t, rb);
        __syncthreads();
    }
}

extern "C" void kernel_launch(void* const* d_in, const int* in_sizes, int n_in,
                              void* d_out, int out_size, void* d_ws, size_t ws_size,
                              hipStream_t stream) {
    const float* q = (const float*)d_in[0];
    const float* k = (const float*)d_in[1];
    const float* v = (const float*)d_in[2];
    float* o = (float*)d_out;
    dim3 grid(NUNITS);   // 1600 blocks of 256
    box_attn_kernel<<<grid, NT, 0, stream>>>(q, k, v, o);
}

// Round 8
// 228.790 us; speedup vs baseline: 2.3747x; 1.2719x over previous
//
#include <hip/hip_runtime.h>

// Per-pixel attention over 32 "boxes" (all fp32):
//   q,k,v: [32 box][4 batch][64 ch][6400 pix]
//   scores[i,j] = <q[i,:,p], k[j,:,p]> / 8 ; w = softmax_j ; out[i,c,p] = sum_j w[i,j] v[j,c,p]
//
// R8 vs R7: R7 (rolled chunk loops) FAILED post-timing revalidation (absmax 0.656 after
// graph replays; first run passed) -> timing-dependent divergence = intra-launch race.
// The double-buffer barrier induction is sound in source order; the suspect is the
// scheduler moving next-iteration ds_reads above the barrier in the ROLLED loop
// (R5/R6 with identical buffering but unrolled loops passed; guide rule #18 documents
// hipcc reordering around barrier-adjacent waits). Fix: __builtin_amdgcn_sched_barrier(0)
// immediately before and after every __syncthreads() -- a compile-time fence, zero
// runtime instructions, nothing may cross. Everything else identical to R7.

#define NBOX    32
#define NBATCH  4
#define CH      64
#define HW      6400
#define PIX     16
#define CC      4
#define NCHUNK  (CH / CC)          // 16
#define IB      2
#define NT      256
#define LPJ     36                 // LDS row stride in floats (32 j + 4 pad)
#define NTILES  (HW / PIX)         // 400
#define NUNITS  (NBATCH * NTILES)  // 1600
#define CSTRIDE ((size_t)CC * HW)  // elements per chunk step

#define SYNC() do { __builtin_amdgcn_sched_barrier(0); __syncthreads(); \
                    __builtin_amdgcn_sched_barrier(0); } while (0)

__global__ __launch_bounds__(NT, 2)
void box_attn_kernel(const float* __restrict__ q,
                     const float* __restrict__ k,
                     const float* __restrict__ v,
                     float* __restrict__ out) {
    __shared__ float lds[2][CC * PIX * LPJ];   // 2 x 9.2 KiB

    const int t   = threadIdx.x;
    const int bid = blockIdx.x;
    const int unit = (bid & 7) * (NUNITS / 8) + (bid >> 3);  // XCD swizzle (1600%8==0)
    const int b    = unit / NTILES;
    const int p0   = (unit % NTILES) * PIX;

    const int pp = t & (PIX - 1);
    const int i0 = (t >> 4) * IB;

    // ---- staging geometry: thread t covers (pg,jj,cs) and channel cs+2 (2nd float4) ----
    const int pg = t & 3;                 // pixel group of 4
    const int jj = (t >> 2) & 31;         // box
    const int cs = t >> 7;                // channel-within-chunk (0..1); 2nd load adds 2
    const size_t g0 = ((size_t)(jj * NBATCH + b) * CH + cs) * HW + p0 + pg * 4;
    const size_t gd = (size_t)2 * HW;     // 2nd load global delta
    const int    l0 = (cs * PIX + pg * 4) * LPJ + jj;
    const int    ld = 2 * PIX * LPJ;      // 2nd load lds delta

    const size_t qoff0 = ((size_t)((i0 + 0) * NBATCH + b) * CH) * HW + p0 + pp;
    const size_t qoff1 = ((size_t)((i0 + 1) * NBATCH + b) * CH) * HW + p0 + pp;

    float s0[NBOX], s1[NBOX];
#pragma unroll
    for (int j = 0; j < NBOX; ++j) { s0[j] = 0.f; s1[j] = 0.f; }

    float4 rb0, rb1;

    // ================= Phase 1: scores = Q.K (1/8 folded into softmax) =================
    rb0 = *reinterpret_cast<const float4*>(k + g0);
    rb1 = *reinterpret_cast<const float4*>(k + g0 + gd);
    {
        float* d0 = &lds[0][l0];
        d0[0] = rb0.x; d0[LPJ] = rb0.y; d0[2 * LPJ] = rb0.z; d0[3 * LPJ] = rb0.w;
        float* d1 = &lds[0][l0 + ld];
        d1[0] = rb1.x; d1[LPJ] = rb1.y; d1[2 * LPJ] = rb1.z; d1[3 * LPJ] = rb1.w;
    }
    SYNC();

#pragma unroll 1
    for (int ch = 0; ch < NCHUNK; ++ch) {
        const bool pre = (ch + 1 < NCHUNK);
        if (pre) {
            const float* src = k + g0 + (size_t)(ch + 1) * CSTRIDE;
            rb0 = *reinterpret_cast<const float4*>(src);
            rb1 = *reinterpret_cast<const float4*>(src + gd);
        }

        float qf0[CC], qf1[CC];
#pragma unroll
        for (int c = 0; c < CC; ++c) {
            qf0[c] = q[qoff0 + (size_t)(ch * CC + c) * HW];
            qf1[c] = q[qoff1 + (size_t)(ch * CC + c) * HW];
        }

        const float* buf = &lds[ch & 1][0];
#pragma unroll
        for (int c = 0; c < CC; ++c) {
            const float* row = &buf[(c * PIX + pp) * LPJ];
#pragma unroll
            for (int jg = 0; jg < 8; ++jg) {
                float4 kv = *reinterpret_cast<const float4*>(row + jg * 4);
                s0[jg * 4 + 0] = fmaf(qf0[c], kv.x, s0[jg * 4 + 0]);
                s0[jg * 4 + 1] = fmaf(qf0[c], kv.y, s0[jg * 4 + 1]);
                s0[jg * 4 + 2] = fmaf(qf0[c], kv.z, s0[jg * 4 + 2]);
                s0[jg * 4 + 3] = fmaf(qf0[c], kv.w, s0[jg * 4 + 3]);
                s1[jg * 4 + 0] = fmaf(qf1[c], kv.x, s1[jg * 4 + 0]);
                s1[jg * 4 + 1] = fmaf(qf1[c], kv.y, s1[jg * 4 + 1]);
                s1[jg * 4 + 2] = fmaf(qf1[c], kv.z, s1[jg * 4 + 2]);
                s1[jg * 4 + 3] = fmaf(qf1[c], kv.w, s1[jg * 4 + 3]);
            }
        }

        if (pre) {
            float* d0 = &lds[(ch + 1) & 1][l0];
            d0[0] = rb0.x; d0[LPJ] = rb0.y; d0[2 * LPJ] = rb0.z; d0[3 * LPJ] = rb0.w;
            float* d1 = &lds[(ch + 1) & 1][l0 + ld];
            d1[0] = rb1.x; d1[LPJ] = rb1.y; d1[2 * LPJ] = rb1.z; d1[3 * LPJ] = rb1.w;
        }
        SYNC();
    }

    // ================= softmax over j (in-register; scale folded) =================
    rb0 = *reinterpret_cast<const float4*>(v + g0);        // overlap V chunk-0 fetch
    rb1 = *reinterpret_cast<const float4*>(v + g0 + gd);
    {
        float m = s0[0];
#pragma unroll
        for (int j = 1; j < NBOX; ++j) m = fmaxf(m, s0[j]);
        float sum = 0.f;
#pragma unroll
        for (int j = 0; j < NBOX; ++j) { float e = __expf((s0[j] - m) * 0.125f); s0[j] = e; sum += e; }
        float inv = 1.f / sum;
#pragma unroll
        for (int j = 0; j < NBOX; ++j) s0[j] *= inv;
    }
    {
        float m = s1[0];
#pragma unroll
        for (int j = 1; j < NBOX; ++j) m = fmaxf(m, s1[j]);
        float sum = 0.f;
#pragma unroll
        for (int j = 0; j < NBOX; ++j) { float e = __expf((s1[j] - m) * 0.125f); s1[j] = e; sum += e; }
        float inv = 1.f / sum;
#pragma unroll
        for (int j = 0; j < NBOX; ++j) s1[j] *= inv;
    }

    // ================= Phase 2: out = W V =================
    {   // all waves passed the final phase-1 barrier -> lds[0] free
        float* d0 = &lds[0][l0];
        d0[0] = rb0.x; d0[LPJ] = rb0.y; d0[2 * LPJ] = rb0.z; d0[3 * LPJ] = rb0.w;
        float* d1 = &lds[0][l0 + ld];
        d1[0] = rb1.x; d1[LPJ] = rb1.y; d1[2 * LPJ] = rb1.z; d1[3 * LPJ] = rb1.w;
    }
    SYNC();

#pragma unroll 1
    for (int ch = 0; ch < NCHUNK; ++ch) {
        const bool pre = (ch + 1 < NCHUNK);
        if (pre) {
            const float* src = v + g0 + (size_t)(ch + 1) * CSTRIDE;
            rb0 = *reinterpret_cast<const float4*>(src);
            rb1 = *reinterpret_cast<const float4*>(src + gd);
        }

        float acc0[CC], acc1[CC];
#pragma unroll
        for (int c = 0; c < CC; ++c) { acc0[c] = 0.f; acc1[c] = 0.f; }

        const float* buf = &lds[ch & 1][0];
#pragma unroll
        for (int c = 0; c < CC; ++c) {
            const float* row = &buf[(c * PIX + pp) * LPJ];
#pragma unroll
            for (int jg = 0; jg < 8; ++jg) {
                float4 vv = *reinterpret_cast<const float4*>(row + jg * 4);
                acc0[c] = fmaf(s0[jg * 4 + 0], vv.x, acc0[c]);
                acc0[c] = fmaf(s0[jg * 4 + 1], vv.y, acc0[c]);
                acc0[c] = fmaf(s0[jg * 4 + 2], vv.z, acc0[c]);
                acc0[c] = fmaf(s0[jg * 4 + 3], vv.w, acc0[c]);
                acc1[c] = fmaf(s1[jg * 4 + 0], vv.x, acc1[c]);
                acc1[c] = fmaf(s1[jg * 4 + 1], vv.y, acc1[c]);
                acc1[c] = fmaf(s1[jg * 4 + 2], vv.z, acc1[c]);
                acc1[c] = fmaf(s1[jg * 4 + 3], vv.w, acc1[c]);
            }
        }
#pragma unroll
        for (int c = 0; c < CC; ++c) {
            out[qoff0 + (size_t)(ch * CC + c) * HW] = acc0[c];
            out[qoff1 + (size_t)(ch * CC + c) * HW] = acc1[c];
        }

        if (pre) {
            float* d0 = &lds[(ch + 1) & 1][l0];
            d0[0] = rb0.x; d0[LPJ] = rb0.y; d0[2 * LPJ] = rb0.z; d0[3 * LPJ] = rb0.w;
            float* d1 = &lds[(ch + 1) & 1][l0 + ld];
            d1[0] = rb1.x; d1[LPJ] = rb1.y; d1[2 * LPJ] = rb1.z; d1[3 * LPJ] = rb1.w;
        }
        SYNC();
    }
}

extern "C" void kernel_launch(void* const* d_in, const int* in_sizes, int n_in,
                              void* d_out, int out_size, void* d_ws, size_t ws_size,
                              hipStream_t stream) {
    const float* q = (const float*)d_in[0];
    const float* k = (const float*)d_in[1];
    const float* v = (const float*)d_in[2];
    float* o = (float*)d_out;
    dim3 grid(NUNITS);   // 1600 blocks of 256
    box_attn_kernel<<<grid, NT, 0, stream>>>(q, k, v, o);
}

// Round 9
// 216.060 us; speedup vs baseline: 2.5146x; 1.0589x over previous
//
#include <hip/hip_runtime.h>

// Per-pixel attention over 32 "boxes" (all fp32):
//   q,k,v: [32 box][4 batch][64 ch][6400 pix]
//   scores[i,j] = <q[i,:,p], k[j,:,p]> / 8 ; w = softmax_j ; out[i,c,p] = sum_j w[i,j] v[j,c,p]
//
// R9 vs R8: R8 was latency-bound (VALU 30%, HBM 25%, Occ 19%; composite floor ~100us,
// measured 229us). The unhidden stalls: (a) per-chunk Q loads used immediately (~900cy
// HBM stall mid-chunk, 32x/wave); (b) V prefetch only 1 chunk (~512cy) deep. Fix:
//   1. Q register double-buffer: qn loads for ch+1 issued at top of ch, copied to qf
//      after the barrier (~700+cy cover). +16 VGPR.
//   2. Phase-2 V prefetch 2-deep (load V[ch+2] at ch; write V[ch+1] at end of ch)
//      -> ~1000cy in flight. Phase 2 has no Q loads so the regs are free.
// Register budget ~100-110/phase, under the 128 cap (launch_bounds(256,2), the only
// measured no-spill point). All else = R8: double-buffered LDS, sched_barrier-fenced
// SYNC (R7's replay race fix), PIX=16 broadcast LDS reads, XCD swizzle, 1600 blocks.

#define NBOX    32
#define NBATCH  4
#define CH      64
#define HW      6400
#define PIX     16
#define CC      4
#define NCHUNK  (CH / CC)          // 16
#define IB      2
#define NT      256
#define LPJ     36                 // LDS row stride in floats (32 j + 4 pad)
#define NTILES  (HW / PIX)         // 400
#define NUNITS  (NBATCH * NTILES)  // 1600
#define CSTRIDE ((size_t)CC * HW)  // elements per chunk step

#define SYNC() do { __builtin_amdgcn_sched_barrier(0); __syncthreads(); \
                    __builtin_amdgcn_sched_barrier(0); } while (0)

__global__ __launch_bounds__(NT, 2)
void box_attn_kernel(const float* __restrict__ q,
                     const float* __restrict__ k,
                     const float* __restrict__ v,
                     float* __restrict__ out) {
    __shared__ float lds[2][CC * PIX * LPJ];   // 2 x 9.2 KiB

    const int t   = threadIdx.x;
    const int bid = blockIdx.x;
    const int unit = (bid & 7) * (NUNITS / 8) + (bid >> 3);  // XCD swizzle (1600%8==0)
    const int b    = unit / NTILES;
    const int p0   = (unit % NTILES) * PIX;

    const int pp = t & (PIX - 1);
    const int i0 = (t >> 4) * IB;

    // ---- staging geometry: thread t covers (pg,jj,cs) and channel cs+2 (2nd float4) ----
    const int pg = t & 3;                 // pixel group of 4
    const int jj = (t >> 2) & 31;         // box
    const int cs = t >> 7;                // channel-within-chunk (0..1); 2nd load adds 2
    const size_t g0 = ((size_t)(jj * NBATCH + b) * CH + cs) * HW + p0 + pg * 4;
    const size_t gd = (size_t)2 * HW;     // 2nd load global delta
    const int    l0 = (cs * PIX + pg * 4) * LPJ + jj;
    const int    ld = 2 * PIX * LPJ;      // 2nd load lds delta

    const size_t qoff0 = ((size_t)((i0 + 0) * NBATCH + b) * CH) * HW + p0 + pp;
    const size_t qoff1 = ((size_t)((i0 + 1) * NBATCH + b) * CH) * HW + p0 + pp;

    float s0[NBOX], s1[NBOX];
#pragma unroll
    for (int j = 0; j < NBOX; ++j) { s0[j] = 0.f; s1[j] = 0.f; }

    float4 rb0, rb1;

    // ================= Phase 1: scores = Q.K (1/8 folded into softmax) =================
    rb0 = *reinterpret_cast<const float4*>(k + g0);
    rb1 = *reinterpret_cast<const float4*>(k + g0 + gd);
    {
        float* d0 = &lds[0][l0];
        d0[0] = rb0.x; d0[LPJ] = rb0.y; d0[2 * LPJ] = rb0.z; d0[3 * LPJ] = rb0.w;
        float* d1 = &lds[0][l0 + ld];
        d1[0] = rb1.x; d1[LPJ] = rb1.y; d1[2 * LPJ] = rb1.z; d1[3 * LPJ] = rb1.w;
    }
    // Q chunk-0 prefetch (in flight across the barrier)
    float qf0[CC], qf1[CC], qn0[CC], qn1[CC];
#pragma unroll
    for (int c = 0; c < CC; ++c) {
        qf0[c] = q[qoff0 + (size_t)c * HW];
        qf1[c] = q[qoff1 + (size_t)c * HW];
    }
    SYNC();

#pragma unroll 1
    for (int ch = 0; ch < NCHUNK; ++ch) {
        const bool pre = (ch + 1 < NCHUNK);
        if (pre) {
            const float* src = k + g0 + (size_t)(ch + 1) * CSTRIDE;
            rb0 = *reinterpret_cast<const float4*>(src);
            rb1 = *reinterpret_cast<const float4*>(src + gd);
#pragma unroll
            for (int c = 0; c < CC; ++c) {         // Q prefetch for ch+1
                qn0[c] = q[qoff0 + (size_t)((ch + 1) * CC + c) * HW];
                qn1[c] = q[qoff1 + (size_t)((ch + 1) * CC + c) * HW];
            }
        }

        const float* buf = &lds[ch & 1][0];
#pragma unroll
        for (int c = 0; c < CC; ++c) {
            const float* row = &buf[(c * PIX + pp) * LPJ];
#pragma unroll
            for (int jg = 0; jg < 8; ++jg) {
                float4 kv = *reinterpret_cast<const float4*>(row + jg * 4);
                s0[jg * 4 + 0] = fmaf(qf0[c], kv.x, s0[jg * 4 + 0]);
                s0[jg * 4 + 1] = fmaf(qf0[c], kv.y, s0[jg * 4 + 1]);
                s0[jg * 4 + 2] = fmaf(qf0[c], kv.z, s0[jg * 4 + 2]);
                s0[jg * 4 + 3] = fmaf(qf0[c], kv.w, s0[jg * 4 + 3]);
                s1[jg * 4 + 0] = fmaf(qf1[c], kv.x, s1[jg * 4 + 0]);
                s1[jg * 4 + 1] = fmaf(qf1[c], kv.y, s1[jg * 4 + 1]);
                s1[jg * 4 + 2] = fmaf(qf1[c], kv.z, s1[jg * 4 + 2]);
                s1[jg * 4 + 3] = fmaf(qf1[c], kv.w, s1[jg * 4 + 3]);
            }
        }

        if (pre) {
            float* d0 = &lds[(ch + 1) & 1][l0];
            d0[0] = rb0.x; d0[LPJ] = rb0.y; d0[2 * LPJ] = rb0.z; d0[3 * LPJ] = rb0.w;
            float* d1 = &lds[(ch + 1) & 1][l0 + ld];
            d1[0] = rb1.x; d1[LPJ] = rb1.y; d1[2 * LPJ] = rb1.z; d1[3 * LPJ] = rb1.w;
        }
        SYNC();
        if (pre) {
#pragma unroll
            for (int c = 0; c < CC; ++c) { qf0[c] = qn0[c]; qf1[c] = qn1[c]; }
        }
    }

    // ================= softmax over j (in-register; scale folded) =================
    rb0 = *reinterpret_cast<const float4*>(v + g0);        // V chunk-0 fetch overlaps softmax
    rb1 = *reinterpret_cast<const float4*>(v + g0 + gd);
    {
        float m = s0[0];
#pragma unroll
        for (int j = 1; j < NBOX; ++j) m = fmaxf(m, s0[j]);
        float sum = 0.f;
#pragma unroll
        for (int j = 0; j < NBOX; ++j) { float e = __expf((s0[j] - m) * 0.125f); s0[j] = e; sum += e; }
        float inv = 1.f / sum;
#pragma unroll
        for (int j = 0; j < NBOX; ++j) s0[j] *= inv;
    }
    {
        float m = s1[0];
#pragma unroll
        for (int j = 1; j < NBOX; ++j) m = fmaxf(m, s1[j]);
        float sum = 0.f;
#pragma unroll
        for (int j = 0; j < NBOX; ++j) { float e = __expf((s1[j] - m) * 0.125f); s1[j] = e; sum += e; }
        float inv = 1.f / sum;
#pragma unroll
        for (int j = 0; j < NBOX; ++j) s1[j] *= inv;
    }

    // ================= Phase 2: out = W V (V prefetch 2 chunks deep) =================
    float4 rA0, rA1, rB0, rB1;
    {   // all waves passed the final phase-1 barrier -> lds[0] free
        float* d0 = &lds[0][l0];
        d0[0] = rb0.x; d0[LPJ] = rb0.y; d0[2 * LPJ] = rb0.z; d0[3 * LPJ] = rb0.w;
        float* d1 = &lds[0][l0 + ld];
        d1[0] = rb1.x; d1[LPJ] = rb1.y; d1[2 * LPJ] = rb1.z; d1[3 * LPJ] = rb1.w;
    }
    {   // V chunk-1 prefetch, in flight across the barrier
        const float* src = v + g0 + CSTRIDE;
        rA0 = *reinterpret_cast<const float4*>(src);
        rA1 = *reinterpret_cast<const float4*>(src + gd);
    }
    SYNC();

#pragma unroll 1
    for (int ch = 0; ch < NCHUNK; ++ch) {
        if (ch + 2 < NCHUNK) {                     // V chunk ch+2 prefetch
            const float* src = v + g0 + (size_t)(ch + 2) * CSTRIDE;
            rB0 = *reinterpret_cast<const float4*>(src);
            rB1 = *reinterpret_cast<const float4*>(src + gd);
        }

        float acc0[CC], acc1[CC];
#pragma unroll
        for (int c = 0; c < CC; ++c) { acc0[c] = 0.f; acc1[c] = 0.f; }

        const float* buf = &lds[ch & 1][0];
#pragma unroll
        for (int c = 0; c < CC; ++c) {
            const float* row = &buf[(c * PIX + pp) * LPJ];
#pragma unroll
            for (int jg = 0; jg < 8; ++jg) {
                float4 vv = *reinterpret_cast<const float4*>(row + jg * 4);
                acc0[c] = fmaf(s0[jg * 4 + 0], vv.x, acc0[c]);
                acc0[c] = fmaf(s0[jg * 4 + 1], vv.y, acc0[c]);
                acc0[c] = fmaf(s0[jg * 4 + 2], vv.z, acc0[c]);
                acc0[c] = fmaf(s0[jg * 4 + 3], vv.w, acc0[c]);
                acc1[c] = fmaf(s1[jg * 4 + 0], vv.x, acc1[c]);
                acc1[c] = fmaf(s1[jg * 4 + 1], vv.y, acc1[c]);
                acc1[c] = fmaf(s1[jg * 4 + 2], vv.z, acc1[c]);
                acc1[c] = fmaf(s1[jg * 4 + 3], vv.w, acc1[c]);
            }
        }
#pragma unroll
        for (int c = 0; c < CC; ++c) {
            out[qoff0 + (size_t)(ch * CC + c) * HW] = acc0[c];
            out[qoff1 + (size_t)(ch * CC + c) * HW] = acc1[c];
        }

        if (ch + 1 < NCHUNK) {                     // write V chunk ch+1 (loaded 2 chunks ago)
            float* d0 = &lds[(ch + 1) & 1][l0];
            d0[0] = rA0.x; d0[LPJ] = rA0.y; d0[2 * LPJ] = rA0.z; d0[3 * LPJ] = rA0.w;
            float* d1 = &lds[(ch + 1) & 1][l0 + ld];
            d1[0] = rA1.x; d1[LPJ] = rA1.y; d1[2 * LPJ] = rA1.z; d1[3 * LPJ] = rA1.w;
        }
        SYNC();
        if (ch + 2 < NCHUNK) { rA0 = rB0; rA1 = rB1; }
    }
}

extern "C" void kernel_launch(void* const* d_in, const int* in_sizes, int n_in,
                              void* d_out, int out_size, void* d_ws, size_t ws_size,
                              hipStream_t stream) {
    const float* q = (const float*)d_in[0];
    const float* k = (const float*)d_in[1];
    const float* v = (const float*)d_in[2];
    float* o = (float*)d_out;
    dim3 grid(NUNITS);   // 1600 blocks of 256
    box_attn_kernel<<<grid, NT, 0, stream>>>(q, k, v, o);
}